// Round 5
// baseline (18.320 us; speedup 1.0000x reference)
//
#include <hip/hip_runtime.h>
#include <hip/hip_bf16.h>

// Embedding gather: out[b,s,:] = table[x[b,s], :]
// x: [4,2048] int32 (8192 tokens), table: [32000,128] f32, out: [8192,128] f32.
// R5: one f32x2 (8B) per thread -> 524288 threads = 8192 waves = 8 waves/SIMD
// (max occupancy; R1's 16B/thread gave only 4 waves/SIMD). Doubles the
// latency-hiding pool for the idx->row dependent chain. Loads stay coalesced
// (64 lanes x 8B = 512B per instruction).

typedef float f32x2 __attribute__((ext_vector_type(2)));

__global__ __launch_bounds__(256) void embedding_gather_kernel(
    const int* __restrict__ x,
    const f32x2* __restrict__ table,    // [32000][64] f32x2
    f32x2* __restrict__ out,            // [8192][64] f32x2
    int n_tokens)
{
    int gid = blockIdx.x * blockDim.x + threadIdx.x;   // one f32x2 per thread
    int token = gid >> 6;          // gid / 64   (128 f32 = 64 f32x2 per row)
    int elem  = gid & 63;          // gid % 64
    if (token < n_tokens) {
        int row = x[token];
        out[(size_t)token * 64 + elem] = table[(size_t)row * 64 + elem];
    }
}

extern "C" void kernel_launch(void* const* d_in, const int* in_sizes, int n_in,
                              void* d_out, int out_size, void* d_ws, size_t ws_size,
                              hipStream_t stream) {
    const int*   x     = (const int*)d_in[0];
    const f32x2* table = (const f32x2*)d_in[1];
    f32x2*       out   = (f32x2*)d_out;

    const int n_tokens = in_sizes[0];            // 8192
    const int total    = n_tokens * 64;          // f32x2 units (524288)
    const int block    = 256;
    const int grid     = (total + block - 1) / block;   // 2048

    embedding_gather_kernel<<<grid, block, 0, stream>>>(x, table, out, n_tokens);
}

// Round 6
// 9.757 us; speedup vs baseline: 1.8776x; 1.8776x over previous
//
#include <hip/hip_runtime.h>
#include <hip/hip_bf16.h>

// Embedding gather: out[b,s,:] = table[x[b,s], :]
// x: [4,2048] int32 (8192 tokens), table: [32000,128] f32, out: [8192,128] f32.
// R6: identical per-thread work to R1 (one 16B f32x4 per thread, 32
// threads/token, 4096 waves total) but 256 blocks x 1024 threads instead of
// 1024 x 256 -> 4x fewer workgroups for the command processor to dispatch.
// R1=9.7us, R2(2-chain)=12.3, R5(8B/thread)=18.3: exec portion scales with
// VMEM instruction count (cold cache every replay; 16B/lane is the sweet
// spot); this round isolates workgroup-dispatch overhead.

typedef float f32x4 __attribute__((ext_vector_type(4)));

__global__ __launch_bounds__(1024) void embedding_gather_kernel(
    const int* __restrict__ x,
    const f32x4* __restrict__ table,    // [32000][32] f32x4
    f32x4* __restrict__ out,            // [8192][32] f32x4
    int n_tokens)
{
    int gid = blockIdx.x * blockDim.x + threadIdx.x;   // one f32x4 per thread
    int token = gid >> 5;          // gid / 32
    int elem  = gid & 31;          // gid % 32
    if (token < n_tokens) {
        int row = x[token];
        out[(size_t)token * 32 + elem] = table[(size_t)row * 32 + elem];
    }
}

extern "C" void kernel_launch(void* const* d_in, const int* in_sizes, int n_in,
                              void* d_out, int out_size, void* d_ws, size_t ws_size,
                              hipStream_t stream) {
    const int*   x     = (const int*)d_in[0];
    const f32x4* table = (const f32x4*)d_in[1];
    f32x4*       out   = (f32x4*)d_out;

    const int n_tokens = in_sizes[0];            // 8192
    const int total    = n_tokens * 32;          // f32x4 units (262144)
    const int block    = 1024;
    const int grid     = (total + block - 1) / block;   // 256

    embedding_gather_kernel<<<grid, block, 0, stream>>>(x, table, out, n_tokens);
}